// Round 4
// baseline (266.402 us; speedup 1.0000x reference)
//
#include <hip/hip_runtime.h>
#include <stdint.h>
#include <stddef.h>

typedef unsigned short u16;
typedef __bf16 bf16x8 __attribute__((ext_vector_type(8)));
typedef float f32x4 __attribute__((ext_vector_type(4)));
typedef u16 u16x8 __attribute__((ext_vector_type(8)));

#define SEQ    1024
#define DEMB   1024
#define MROWS  4096
#define NHEAD  16
#define HD     64
#define QSCALE 0.125f
#define LN_EPS 1e-5f

// round-to-nearest-even fp32 -> bf16 (raw bits)
static __device__ __forceinline__ u16 f2bf(float f) {
  union { float f; unsigned u; } c; c.f = f;
  unsigned r = c.u + 0x7FFFu + ((c.u >> 16) & 1u);
  return (u16)(r >> 16);
}
static __device__ __forceinline__ float bf2f(unsigned h) {
  union { unsigned u; float f; } c; c.u = h << 16; return c.f;
}

// async global->LDS, 16B per lane; LDS dest = wave-uniform base + lane*16
static __device__ __forceinline__ void gload16(const void* g, void* l) {
  __builtin_amdgcn_global_load_lds((const __attribute__((address_space(1))) void*)g,
                                   (__attribute__((address_space(3))) void*)l, 16, 0, 0);
}

// ---------------- fp32 -> bf16 convert: x (4M) + Wq/Wk/Wv/Wo (4M) -----------
__global__ void cvt_kernel(const float* __restrict__ x,
                           const float* __restrict__ wq, const float* __restrict__ wk,
                           const float* __restrict__ wv, const float* __restrict__ wo,
                           u16* __restrict__ xb, u16* __restrict__ wb) {
  size_t e = ((size_t)blockIdx.x * blockDim.x + threadIdx.x) * 8;
  const float* src; u16* dst; size_t off;
  if (e < (size_t)MROWS * DEMB) { src = x; dst = xb; off = e; }
  else {
    size_t we = e - (size_t)MROWS * DEMB;
    int plane = (int)(we >> 20);
    src = (plane == 0) ? wq : (plane == 1) ? wk : (plane == 2) ? wv : wo;
    dst = wb + ((size_t)plane << 20);
    off = we & ((1u << 20) - 1);
  }
  float4 a = *(const float4*)(src + off);
  float4 b = *(const float4*)(src + off + 4);
  u16 o[8] = { f2bf(a.x), f2bf(a.y), f2bf(a.z), f2bf(a.w),
               f2bf(b.x), f2bf(b.y), f2bf(b.z), f2bf(b.w) };
  uint4 pk;
  pk.x = (unsigned)o[0] | ((unsigned)o[1] << 16);
  pk.y = (unsigned)o[2] | ((unsigned)o[3] << 16);
  pk.z = (unsigned)o[4] | ((unsigned)o[5] << 16);
  pk.w = (unsigned)o[6] | ((unsigned)o[7] << 16);
  *(uint4*)(dst + off) = pk;
}

// ---------------- bf16 GEMM  C[m,n] = sum_k A[m,k] * W[n,k]  (bf16 out) -----
// m97 structure: 128x128 tile, BK=32, 4 waves each 64x64, global_load_lds.
__global__ __launch_bounds__(256)
void gemm_bt(const u16* __restrict__ A, const u16* __restrict__ B0,
             const u16* __restrict__ B1, const u16* __restrict__ B2,
             u16* __restrict__ C, int M, int N, int K) {
  __shared__ u16 lA[128 * 32];
  __shared__ u16 lB[128 * 32];
  const u16* Bp = (blockIdx.z == 0) ? B0 : (blockIdx.z == 1) ? B1 : B2;
  u16* Cp = C + (size_t)blockIdx.z * ((size_t)M * N);
  const int tid = threadIdx.x;
  const int w = tid >> 6, l = tid & 63;
  const int lr = l & 15, lg = l >> 4;
  const int m0 = blockIdx.x * 128, n0 = blockIdx.y * 128;
  const int wm = (w & 1) * 64, wn = (w >> 1) * 64;
  f32x4 acc[4][4] = {};
  const int cid0 = w * 64 + l;        // chunk ids (16B units), issue 0/1
  const int cid1 = 256 + w * 64 + l;
  const int rowA0 = cid0 >> 2, kc0 = (cid0 & 3) * 8;
  const int rowA1 = cid1 >> 2, kc1 = (cid1 & 3) * 8;
  for (int kt = 0; kt < K; kt += 32) {
    __syncthreads();
    gload16(A  + (size_t)(m0 + rowA0) * K + kt + kc0, lA + (size_t)(w * 64) * 8);
    gload16(A  + (size_t)(m0 + rowA1) * K + kt + kc1, lA + (size_t)(256 + w * 64) * 8);
    gload16(Bp + (size_t)(n0 + rowA0) * K + kt + kc0, lB + (size_t)(w * 64) * 8);
    gload16(Bp + (size_t)(n0 + rowA1) * K + kt + kc1, lB + (size_t)(256 + w * 64) * 8);
    __syncthreads();
    bf16x8 af[4], bfg[4];
#pragma unroll
    for (int mb = 0; mb < 4; ++mb)
      af[mb] = *(const bf16x8*)(lA + (wm + mb * 16 + lr) * 32 + lg * 8);
#pragma unroll
    for (int nb = 0; nb < 4; ++nb)
      bfg[nb] = *(const bf16x8*)(lB + (wn + nb * 16 + lr) * 32 + lg * 8);
#pragma unroll
    for (int mb = 0; mb < 4; ++mb)
#pragma unroll
      for (int nb = 0; nb < 4; ++nb)
        acc[mb][nb] = __builtin_amdgcn_mfma_f32_16x16x32_bf16(af[mb], bfg[nb], acc[mb][nb], 0, 0, 0);
  }
#pragma unroll
  for (int mb = 0; mb < 4; ++mb)
#pragma unroll
    for (int nb = 0; nb < 4; ++nb)
#pragma unroll
      for (int r = 0; r < 4; ++r) {
        int row = m0 + wm + mb * 16 + lg * 4 + r;
        int col = n0 + wn + nb * 16 + lr;
        Cp[(size_t)row * N + col] = f2bf(acc[mb][nb][r]);
      }
}

// ---------------- block-wide (256t) sum + sumsq reduce ----------------------
static __device__ __forceinline__ void block_reduce2(float& s1, float& s2, float* red) {
#pragma unroll
  for (int o = 32; o > 0; o >>= 1) { s1 += __shfl_xor(s1, o); s2 += __shfl_xor(s2, o); }
  int w = threadIdx.x >> 6, l = threadIdx.x & 63;
  if (l == 0) { red[w * 2] = s1; red[w * 2 + 1] = s2; }
  __syncthreads();
  s1 = red[0] + red[2] + red[4] + red[6];
  s2 = red[1] + red[3] + red[5] + red[7];
}

// ---------------- LN over QKV proj rows -> bf16 head layout [B,H,S,64] ------
__global__ void ln_qkv_kernel(const u16* __restrict__ projb,
                              const float* __restrict__ bq, const float* __restrict__ bk,
                              const float* __restrict__ bv,
                              const float* __restrict__ qg, const float* __restrict__ qb,
                              const float* __restrict__ kg, const float* __restrict__ kb,
                              const float* __restrict__ vg, const float* __restrict__ vb,
                              u16* __restrict__ Qh, u16* __restrict__ Kh, u16* __restrict__ Vh) {
  __shared__ float red[8];
  const int row = blockIdx.x & (MROWS - 1);
  const int plane = blockIdx.x >> 12;
  const float* bias; const float* gam; const float* bet; u16* op; float scl;
  if (plane == 0)      { bias = bq; gam = qg; bet = qb; op = Qh; scl = QSCALE; }
  else if (plane == 1) { bias = bk; gam = kg; bet = kb; op = Kh; scl = 1.f; }
  else                 { bias = bv; gam = vg; bet = vb; op = Vh; scl = 1.f; }
  const u16* src = projb + ((size_t)plane * MROWS + row) * DEMB;
  const int t = threadIdx.x;
  uint2 pv = *(const uint2*)(src + t * 4);
  float4 v;
  v.x = bf2f(pv.x & 0xffffu); v.y = bf2f(pv.x >> 16);
  v.z = bf2f(pv.y & 0xffffu); v.w = bf2f(pv.y >> 16);
  float4 bz = *(const float4*)(bias + t * 4);
  v.x += bz.x; v.y += bz.y; v.z += bz.z; v.w += bz.w;
  float s1 = v.x + v.y + v.z + v.w;
  float s2 = v.x * v.x + v.y * v.y + v.z * v.z + v.w * v.w;
  block_reduce2(s1, s2, red);
  const float mean = s1 * (1.f / DEMB);
  const float var = s2 * (1.f / DEMB) - mean * mean;
  const float rstd = rsqrtf(var + LN_EPS);
  float4 gg = *(const float4*)(gam + t * 4);
  float4 bb = *(const float4*)(bet + t * 4);
  u16 o0 = f2bf(((v.x - mean) * rstd * gg.x + bb.x) * scl);
  u16 o1 = f2bf(((v.y - mean) * rstd * gg.y + bb.y) * scl);
  u16 o2 = f2bf(((v.z - mean) * rstd * gg.z + bb.z) * scl);
  u16 o3 = f2bf(((v.w - mean) * rstd * gg.w + bb.w) * scl);
  const int b = row >> 10, s = row & (SEQ - 1);
  const int h = t >> 4;                       // head = (t*4)>>6
  u16* dst = op + ((size_t)(b * NHEAD + h) * SEQ + s) * HD + (t & 15) * 4;
  uint2 pk;
  pk.x = (unsigned)o0 | ((unsigned)o1 << 16);
  pk.y = (unsigned)o2 | ((unsigned)o3 << 16);
  *(uint2*)dst = pk;
}

// ---------------- attention: 1 block = (b,h, 64 q-rows); 4 waves x 16 rows --
// clip(+-10) bounds scores -> exp without max-tracking; fp32 row-sum; PV via
// LDS-transposed V ([64][72] pad = conflict-free) and P relayout in LDS.
__global__ __launch_bounds__(256)
void attn_kernel(const u16* __restrict__ Qh, const u16* __restrict__ Kh,
                 const u16* __restrict__ Vh, u16* __restrict__ AO) {
  __shared__ u16 Vt[64][72];        // V^T tile: [d][kk], padded
  __shared__ u16 Pt[4][16][72];     // per-wave P: [qlocal][kk], padded
  const int qt = blockIdx.x & 15, bh = blockIdx.x >> 4;
  const int b = bh >> 4, h = bh & 15;
  const u16* Qp = Qh + (size_t)bh * SEQ * HD;
  const u16* Kp = Kh + (size_t)bh * SEQ * HD;
  const u16* Vp = Vh + (size_t)bh * SEQ * HD;
  const int tid = threadIdx.x, w = tid >> 6, l = tid & 63;
  const int lr = l & 15, lg = l >> 4;
  const int qrow = qt * 64 + w * 16 + lr;
  bf16x8 qa0 = *(const bf16x8*)(Qp + (size_t)qrow * HD + lg * 8);
  bf16x8 qa1 = *(const bf16x8*)(Qp + (size_t)qrow * HD + 32 + lg * 8);
  f32x4 o[4] = {};
  float rs[4] = {0.f, 0.f, 0.f, 0.f};
  for (int kt = 0; kt < SEQ / 64; ++kt) {
    __syncthreads();                       // prev tile's LDS fully consumed
    // stage V transposed: lane l handles kk=l, d-chunks w*2+i
#pragma unroll
    for (int i = 0; i < 2; ++i) {
      const int dc = w * 2 + i;
      u16x8 vv = *(const u16x8*)(Vp + (size_t)(kt * 64 + l) * HD + dc * 8);
#pragma unroll
      for (int ee = 0; ee < 8; ++ee) Vt[dc * 8 + ee][l] = vv[ee];
    }
    // QK^T: B-frags (K rows) direct from global (L2-resident)
#pragma unroll
    for (int kb = 0; kb < 4; ++kb) {
      const u16* kr = Kp + (size_t)(kt * 64 + kb * 16 + lr) * HD + lg * 8;
      bf16x8 k0 = *(const bf16x8*)kr;
      bf16x8 k1 = *(const bf16x8*)(kr + 32);
      f32x4 sv = {};
      sv = __builtin_amdgcn_mfma_f32_16x16x32_bf16(qa0, k0, sv, 0, 0, 0);
      sv = __builtin_amdgcn_mfma_f32_16x16x32_bf16(qa1, k1, sv, 0, 0, 0);
#pragma unroll
      for (int r = 0; r < 4; ++r) {
        float xx = fminf(10.f, fmaxf(-10.f, sv[r]));
        float p = exp2f(xx * 1.4426950408889634f);   // exp(xx)
        rs[r] += p;                                  // partial row-sum (cols lr)
        Pt[w][lg * 4 + r][kb * 16 + lr] = f2bf(p);
      }
    }
    __syncthreads();                       // Vt + Pt visible
    // PV: O += P @ V
    bf16x8 pa0 = *(const bf16x8*)(&Pt[w][lr][lg * 8]);
    bf16x8 pa1 = *(const bf16x8*)(&Pt[w][lr][32 + lg * 8]);
#pragma unroll
    for (int nb = 0; nb < 4; ++nb) {
      bf16x8 v0 = *(const bf16x8*)(&Vt[nb * 16 + lr][lg * 8]);
      bf16x8 v1 = *(const bf16x8*)(&Vt[nb * 16 + lr][32 + lg * 8]);
      o[nb] = __builtin_amdgcn_mfma_f32_16x16x32_bf16(pa0, v0, o[nb], 0, 0, 0);
      o[nb] = __builtin_amdgcn_mfma_f32_16x16x32_bf16(pa1, v1, o[nb], 0, 0, 0);
    }
  }
  // complete row sums across the 16 lanes sharing lg (bits 0..3 = col id)
#pragma unroll
  for (int r = 0; r < 4; ++r) {
    float vsum = rs[r];
    vsum += __shfl_xor(vsum, 1);
    vsum += __shfl_xor(vsum, 2);
    vsum += __shfl_xor(vsum, 4);
    vsum += __shfl_xor(vsum, 8);
    rs[r] = vsum;
  }
  // write attention output back to [B,S,D] bf16 for the out-projection GEMM
#pragma unroll
  for (int nb = 0; nb < 4; ++nb)
#pragma unroll
    for (int r = 0; r < 4; ++r) {
      const int srow = qt * 64 + w * 16 + lg * 4 + r;
      const int col = h * HD + nb * 16 + lr;
      AO[((size_t)b * SEQ + srow) * DEMB + col] = f2bf(o[nb][r] / rs[r]);
    }
}

// ---------------- final LN -> fp32 output -----------------------------------
__global__ void ln_out_kernel(const u16* __restrict__ src0, const float* __restrict__ bo,
                              const float* __restrict__ og, const float* __restrict__ ob,
                              float* __restrict__ out) {
  __shared__ float red[8];
  const int row = blockIdx.x;
  const u16* src = src0 + (size_t)row * DEMB;
  const int t = threadIdx.x;
  uint2 pv = *(const uint2*)(src + t * 4);
  float4 v;
  v.x = bf2f(pv.x & 0xffffu); v.y = bf2f(pv.x >> 16);
  v.z = bf2f(pv.y & 0xffffu); v.w = bf2f(pv.y >> 16);
  float4 bz = *(const float4*)(bo + t * 4);
  v.x += bz.x; v.y += bz.y; v.z += bz.z; v.w += bz.w;
  float s1 = v.x + v.y + v.z + v.w;
  float s2 = v.x * v.x + v.y * v.y + v.z * v.z + v.w * v.w;
  block_reduce2(s1, s2, red);
  const float mean = s1 * (1.f / DEMB);
  const float var = s2 * (1.f / DEMB) - mean * mean;
  const float rstd = rsqrtf(var + LN_EPS);
  float4 gg = *(const float4*)(og + t * 4);
  float4 bb = *(const float4*)(ob + t * 4);
  float4 r;
  r.x = (v.x - mean) * rstd * gg.x + bb.x;
  r.y = (v.y - mean) * rstd * gg.y + bb.y;
  r.z = (v.z - mean) * rstd * gg.z + bb.z;
  r.w = (v.w - mean) * rstd * gg.w + bb.w;
  *(float4*)(out + (size_t)row * DEMB + t * 4) = r;
}

extern "C" void kernel_launch(void* const* d_in, const int* in_sizes, int n_in,
                              void* d_out, int out_size, void* d_ws, size_t ws_size,
                              hipStream_t stream) {
  (void)in_sizes; (void)n_in; (void)out_size; (void)ws_size;
  const float* x  = (const float*)d_in[0];
  const float* Wq = (const float*)d_in[1];
  const float* bq = (const float*)d_in[2];
  const float* Wk = (const float*)d_in[3];
  const float* bk = (const float*)d_in[4];
  const float* Wv = (const float*)d_in[5];
  const float* bv = (const float*)d_in[6];
  const float* Wo = (const float*)d_in[7];
  const float* bo = (const float*)d_in[8];
  const float* qg = (const float*)d_in[9];
  const float* qb = (const float*)d_in[10];
  const float* kg = (const float*)d_in[11];
  const float* kb = (const float*)d_in[12];
  const float* vg = (const float*)d_in[13];
  const float* vb = (const float*)d_in[14];
  const float* og = (const float*)d_in[15];
  const float* ob = (const float*)d_in[16];

  // Workspace: 64 MB total (was 96 MB — defensive vs unknown ws_size).
  char* ws = (char*)d_ws;
  u16* xb    = (u16*)(ws);                        // 8 MB bf16 x; reused as AO after QKV GEMM
  u16* wb    = (u16*)(ws + ((size_t)8  << 20));   // 8 MB bf16 Wq|Wk|Wv|Wo
  u16* projb = (u16*)(ws + ((size_t)16 << 20));   // 24 MB bf16 [3][4096][1024]
  u16* Qh    = (u16*)(ws + ((size_t)40 << 20));   // 8 MB [B,H,S,64]
  u16* Kh    = (u16*)(ws + ((size_t)48 << 20));
  u16* Vh    = (u16*)(ws + ((size_t)56 << 20));   // end: 64 MB
  u16* AOp   = xb;                                // alias: xb dead after QKV GEMM
  u16* oprojb = projb;                            // alias: projb dead after ln_qkv

  cvt_kernel<<<4096, 256, 0, stream>>>(x, Wq, Wk, Wv, Wo, xb, wb);

  dim3 gqkv(32, 8, 3);
  gemm_bt<<<gqkv, 256, 0, stream>>>(xb, wb, wb + (1u << 20), wb + (2u << 20),
                                    projb, MROWS, DEMB, DEMB);

  ln_qkv_kernel<<<3 * MROWS, 256, 0, stream>>>(projb, bq, bk, bv,
                                               qg, qb, kg, kb, vg, vb,
                                               Qh, Kh, Vh);

  attn_kernel<<<1024, 256, 0, stream>>>(Qh, Kh, Vh, AOp);

  dim3 go(32, 8, 1);
  gemm_bt<<<go, 256, 0, stream>>>(AOp, wb + (3u << 20), wb + (3u << 20), wb + (3u << 20),
                                  oprojb, MROWS, DEMB, DEMB);

  ln_out_kernel<<<MROWS, 256, 0, stream>>>(oprojb, bo, og, ob, (float*)d_out);
}

// Round 5
// 262.145 us; speedup vs baseline: 1.0162x; 1.0162x over previous
//
#include <hip/hip_runtime.h>
#include <stdint.h>
#include <stddef.h>

typedef unsigned short u16;
typedef __bf16 bf16x8 __attribute__((ext_vector_type(8)));
typedef float f32x4 __attribute__((ext_vector_type(4)));
typedef u16 u16x8 __attribute__((ext_vector_type(8)));

#define SEQ    1024
#define DEMB   1024
#define MROWS  4096
#define NHEAD  16
#define HD     64
#define QSCALE 0.125f
#define LN_EPS 1e-5f

// round-to-nearest-even fp32 -> bf16 (raw bits)
static __device__ __forceinline__ u16 f2bf(float f) {
  union { float f; unsigned u; } c; c.f = f;
  unsigned r = c.u + 0x7FFFu + ((c.u >> 16) & 1u);
  return (u16)(r >> 16);
}
static __device__ __forceinline__ float bf2f(unsigned h) {
  union { unsigned u; float f; } c; c.u = h << 16; return c.f;
}

// async global->LDS, 16B per lane; LDS dest = wave-uniform base + lane*16
static __device__ __forceinline__ void gload16(const void* g, void* l) {
  __builtin_amdgcn_global_load_lds((const __attribute__((address_space(1))) void*)g,
                                   (__attribute__((address_space(3))) void*)l, 16, 0, 0);
}

// ---------------- fp32 -> bf16 convert: x (4M) + Wq/Wk/Wv/Wo (4M) -----------
__global__ void cvt_kernel(const float* __restrict__ x,
                           const float* __restrict__ wq, const float* __restrict__ wk,
                           const float* __restrict__ wv, const float* __restrict__ wo,
                           u16* __restrict__ xb, u16* __restrict__ wb) {
  size_t e = ((size_t)blockIdx.x * blockDim.x + threadIdx.x) * 8;
  const float* src; u16* dst; size_t off;
  if (e < (size_t)MROWS * DEMB) { src = x; dst = xb; off = e; }
  else {
    size_t we = e - (size_t)MROWS * DEMB;
    int plane = (int)(we >> 20);
    src = (plane == 0) ? wq : (plane == 1) ? wk : (plane == 2) ? wv : wo;
    dst = wb + ((size_t)plane << 20);
    off = we & ((1u << 20) - 1);
  }
  float4 a = *(const float4*)(src + off);
  float4 b = *(const float4*)(src + off + 4);
  u16 o[8] = { f2bf(a.x), f2bf(a.y), f2bf(a.z), f2bf(a.w),
               f2bf(b.x), f2bf(b.y), f2bf(b.z), f2bf(b.w) };
  uint4 pk;
  pk.x = (unsigned)o[0] | ((unsigned)o[1] << 16);
  pk.y = (unsigned)o[2] | ((unsigned)o[3] << 16);
  pk.z = (unsigned)o[4] | ((unsigned)o[5] << 16);
  pk.w = (unsigned)o[6] | ((unsigned)o[7] << 16);
  *(uint4*)(dst + off) = pk;
}

// ---------------- bf16 GEMM  C[m,n] = sum_k A[m,k] * W[n,k]  (bf16 out) -----
__global__ __launch_bounds__(256)
void gemm_bt(const u16* __restrict__ A, const u16* __restrict__ B0,
             const u16* __restrict__ B1, const u16* __restrict__ B2,
             u16* __restrict__ C, int M, int N, int K) {
  __shared__ u16 lA[128 * 32];
  __shared__ u16 lB[128 * 32];
  const u16* Bp = (blockIdx.z == 0) ? B0 : (blockIdx.z == 1) ? B1 : B2;
  u16* Cp = C + (size_t)blockIdx.z * ((size_t)M * N);
  const int tid = threadIdx.x;
  const int w = tid >> 6, l = tid & 63;
  const int lr = l & 15, lg = l >> 4;
  const int m0 = blockIdx.x * 128, n0 = blockIdx.y * 128;
  const int wm = (w & 1) * 64, wn = (w >> 1) * 64;
  f32x4 acc[4][4] = {};
  const int cid0 = w * 64 + l;
  const int cid1 = 256 + w * 64 + l;
  const int rowA0 = cid0 >> 2, kc0 = (cid0 & 3) * 8;
  const int rowA1 = cid1 >> 2, kc1 = (cid1 & 3) * 8;
  for (int kt = 0; kt < K; kt += 32) {
    __syncthreads();
    gload16(A  + (size_t)(m0 + rowA0) * K + kt + kc0, lA + (size_t)(w * 64) * 8);
    gload16(A  + (size_t)(m0 + rowA1) * K + kt + kc1, lA + (size_t)(256 + w * 64) * 8);
    gload16(Bp + (size_t)(n0 + rowA0) * K + kt + kc0, lB + (size_t)(w * 64) * 8);
    gload16(Bp + (size_t)(n0 + rowA1) * K + kt + kc1, lB + (size_t)(256 + w * 64) * 8);
    __syncthreads();
    bf16x8 af[4], bfg[4];
#pragma unroll
    for (int mb = 0; mb < 4; ++mb)
      af[mb] = *(const bf16x8*)(lA + (wm + mb * 16 + lr) * 32 + lg * 8);
#pragma unroll
    for (int nb = 0; nb < 4; ++nb)
      bfg[nb] = *(const bf16x8*)(lB + (wn + nb * 16 + lr) * 32 + lg * 8);
#pragma unroll
    for (int mb = 0; mb < 4; ++mb)
#pragma unroll
      for (int nb = 0; nb < 4; ++nb)
        acc[mb][nb] = __builtin_amdgcn_mfma_f32_16x16x32_bf16(af[mb], bfg[nb], acc[mb][nb], 0, 0, 0);
  }
#pragma unroll
  for (int mb = 0; mb < 4; ++mb)
#pragma unroll
    for (int nb = 0; nb < 4; ++nb)
#pragma unroll
      for (int r = 0; r < 4; ++r) {
        int row = m0 + wm + mb * 16 + lg * 4 + r;
        int col = n0 + wn + nb * 16 + lr;
        Cp[(size_t)row * N + col] = f2bf(acc[mb][nb][r]);
      }
}

// ---------------- block-wide (256t) sum + sumsq reduce ----------------------
static __device__ __forceinline__ void block_reduce2(float& s1, float& s2, float* red) {
#pragma unroll
  for (int o = 32; o > 0; o >>= 1) { s1 += __shfl_xor(s1, o); s2 += __shfl_xor(s2, o); }
  int w = threadIdx.x >> 6, l = threadIdx.x & 63;
  if (l == 0) { red[w * 2] = s1; red[w * 2 + 1] = s2; }
  __syncthreads();
  s1 = red[0] + red[2] + red[4] + red[6];
  s2 = red[1] + red[3] + red[5] + red[7];
}

// ---------------- LN over QKV proj rows -> bf16 head layout [B,H,S,64] ------
__global__ void ln_qkv_kernel(const u16* __restrict__ projb,
                              const float* __restrict__ bq, const float* __restrict__ bk,
                              const float* __restrict__ bv,
                              const float* __restrict__ qg, const float* __restrict__ qb,
                              const float* __restrict__ kg, const float* __restrict__ kb,
                              const float* __restrict__ vg, const float* __restrict__ vb,
                              u16* __restrict__ Qh, u16* __restrict__ Kh, u16* __restrict__ Vh) {
  __shared__ float red[8];
  const int row = blockIdx.x & (MROWS - 1);
  const int plane = blockIdx.x >> 12;
  const float* bias; const float* gam; const float* bet; u16* op; float scl;
  if (plane == 0)      { bias = bq; gam = qg; bet = qb; op = Qh; scl = QSCALE; }
  else if (plane == 1) { bias = bk; gam = kg; bet = kb; op = Kh; scl = 1.f; }
  else                 { bias = bv; gam = vg; bet = vb; op = Vh; scl = 1.f; }
  const u16* src = projb + ((size_t)plane * MROWS + row) * DEMB;
  const int t = threadIdx.x;
  uint2 pv = *(const uint2*)(src + t * 4);
  float4 v;
  v.x = bf2f(pv.x & 0xffffu); v.y = bf2f(pv.x >> 16);
  v.z = bf2f(pv.y & 0xffffu); v.w = bf2f(pv.y >> 16);
  float4 bz = *(const float4*)(bias + t * 4);
  v.x += bz.x; v.y += bz.y; v.z += bz.z; v.w += bz.w;
  float s1 = v.x + v.y + v.z + v.w;
  float s2 = v.x * v.x + v.y * v.y + v.z * v.z + v.w * v.w;
  block_reduce2(s1, s2, red);
  const float mean = s1 * (1.f / DEMB);
  const float var = s2 * (1.f / DEMB) - mean * mean;
  const float rstd = rsqrtf(var + LN_EPS);
  float4 gg = *(const float4*)(gam + t * 4);
  float4 bb = *(const float4*)(bet + t * 4);
  u16 o0 = f2bf(((v.x - mean) * rstd * gg.x + bb.x) * scl);
  u16 o1 = f2bf(((v.y - mean) * rstd * gg.y + bb.y) * scl);
  u16 o2 = f2bf(((v.z - mean) * rstd * gg.z + bb.z) * scl);
  u16 o3 = f2bf(((v.w - mean) * rstd * gg.w + bb.w) * scl);
  const int b = row >> 10, s = row & (SEQ - 1);
  const int h = t >> 4;
  u16* dst = op + ((size_t)(b * NHEAD + h) * SEQ + s) * HD + (t & 15) * 4;
  uint2 pk;
  pk.x = (unsigned)o0 | ((unsigned)o1 << 16);
  pk.y = (unsigned)o2 | ((unsigned)o3 << 16);
  *(uint2*)dst = pk;
}

// ---------------- V transpose: Vtmp[bh][s][d] -> VT[bh][d][s] ---------------
__global__ __launch_bounds__(256)
void vtr_kernel(const u16* __restrict__ Vtmp, u16* __restrict__ VT) {
  __shared__ u16 t[64][72];
  const int stile = blockIdx.x & 15, bh = blockIdx.x >> 4;
  const u16* src = Vtmp + ((size_t)bh * SEQ + stile * 64) * HD;
  const int tid = threadIdx.x;
  {
    const int c0 = tid * 2;             // 16B chunk ids (512 total)
    const int r = c0 >> 3, c = c0 & 7;  // row 0..63, chunk 0..7 (c even)
    uint4 v0 = *(const uint4*)(src + (size_t)r * HD + c * 8);
    uint4 v1 = *(const uint4*)(src + (size_t)r * HD + (c + 1) * 8);
    *(uint4*)&t[r][c * 8] = v0;
    *(uint4*)&t[r][(c + 1) * 8] = v1;
  }
  __syncthreads();
  const int d = tid >> 2, sc = tid & 3;
  u16 buf[16];
#pragma unroll
  for (int j = 0; j < 16; ++j) buf[j] = t[sc * 16 + j][d];
  u16* dst = VT + ((size_t)bh * HD + d) * SEQ + stile * 64 + sc * 16;
  *(uint4*)(dst)     = *(uint4*)&buf[0];
  *(uint4*)(dst + 8) = *(uint4*)&buf[8];
}

// ---------------- attention: 1 wave per block, 32 q-rows, no barriers -------
// K and V^T fragments direct from global (L2-resident, XCD-chunked swizzle);
// P relayout via per-wave LDS (pad 76 -> conflict-free scalar stores).
__global__ __launch_bounds__(64)
void attn_kernel(const u16* __restrict__ Qh, const u16* __restrict__ Kh,
                 const u16* __restrict__ VT, u16* __restrict__ AO) {
  __shared__ u16 Pt[32][76];
  const int bid = blockIdx.x;
  const int wg = (bid & 7) * 256 + (bid >> 3);   // bijective: 2048 = 8*256
  const int qt = wg & 31, bh = wg >> 5;          // 8 heads per XCD chunk
  const int b = bh >> 4, h = bh & 15;
  const u16* Qp = Qh + (size_t)bh * SEQ * HD;
  const u16* Kp = Kh + (size_t)bh * SEQ * HD;
  const u16* Vp = VT + (size_t)bh * HD * SEQ;
  const int l = threadIdx.x;
  const int lr = l & 15, lg = l >> 4;
  bf16x8 qa[2][2];
#pragma unroll
  for (int m = 0; m < 2; ++m) {
    const u16* qr = Qp + (size_t)(qt * 32 + m * 16 + lr) * HD + lg * 8;
    qa[m][0] = *(const bf16x8*)qr;
    qa[m][1] = *(const bf16x8*)(qr + 32);
  }
  f32x4 o[2][4] = {};
  float rs[2][4] = {{0.f,0.f,0.f,0.f},{0.f,0.f,0.f,0.f}};
  for (int kt = 0; kt < SEQ / 64; ++kt) {
    // QK^T: 16 MFMA, K-frags from global
    f32x4 sv[2][4];
#pragma unroll
    for (int kb = 0; kb < 4; ++kb) {
      const u16* kr = Kp + (size_t)(kt * 64 + kb * 16 + lr) * HD + lg * 8;
      bf16x8 k0 = *(const bf16x8*)kr;
      bf16x8 k1 = *(const bf16x8*)(kr + 32);
#pragma unroll
      for (int m = 0; m < 2; ++m) {
        f32x4 s0 = {};
        s0 = __builtin_amdgcn_mfma_f32_16x16x32_bf16(qa[m][0], k0, s0, 0, 0, 0);
        s0 = __builtin_amdgcn_mfma_f32_16x16x32_bf16(qa[m][1], k1, s0, 0, 0, 0);
        sv[m][kb] = s0;
      }
    }
    // softmax numerator (clip bounds exp; no max tracking needed)
#pragma unroll
    for (int m = 0; m < 2; ++m)
#pragma unroll
      for (int kb = 0; kb < 4; ++kb)
#pragma unroll
        for (int r = 0; r < 4; ++r) {
          float xx = fminf(10.f, fmaxf(-10.f, sv[m][kb][r]));
          float p = exp2f(xx * 1.4426950408889634f);
          rs[m][r] += p;
          Pt[m * 16 + lg * 4 + r][kb * 16 + lr] = f2bf(p);
        }
    // P relayout (intra-wave: in-order LDS pipe + lgkmcnt, no barrier)
    bf16x8 pa[2][2];
#pragma unroll
    for (int m = 0; m < 2; ++m) {
      pa[m][0] = *(const bf16x8*)&Pt[m * 16 + lr][lg * 8];
      pa[m][1] = *(const bf16x8*)&Pt[m * 16 + lr][32 + lg * 8];
    }
    // PV: 16 MFMA, V^T-frags from global
#pragma unroll
    for (int nb = 0; nb < 4; ++nb) {
      const u16* vr = Vp + (size_t)(nb * 16 + lr) * SEQ + kt * 64 + lg * 8;
      bf16x8 v0 = *(const bf16x8*)vr;
      bf16x8 v1 = *(const bf16x8*)(vr + 32);
#pragma unroll
      for (int m = 0; m < 2; ++m) {
        o[m][nb] = __builtin_amdgcn_mfma_f32_16x16x32_bf16(pa[m][0], v0, o[m][nb], 0, 0, 0);
        o[m][nb] = __builtin_amdgcn_mfma_f32_16x16x32_bf16(pa[m][1], v1, o[m][nb], 0, 0, 0);
      }
    }
  }
  // complete row sums across the 16 lanes sharing lg (bits 0..3 = col id)
#pragma unroll
  for (int m = 0; m < 2; ++m)
#pragma unroll
    for (int r = 0; r < 4; ++r) {
      float vsum = rs[m][r];
      vsum += __shfl_xor(vsum, 1);
      vsum += __shfl_xor(vsum, 2);
      vsum += __shfl_xor(vsum, 4);
      vsum += __shfl_xor(vsum, 8);
      rs[m][r] = vsum;
    }
  // write attention output to [B,S,D] bf16 for the out-projection GEMM
#pragma unroll
  for (int m = 0; m < 2; ++m)
#pragma unroll
    for (int nb = 0; nb < 4; ++nb)
#pragma unroll
      for (int r = 0; r < 4; ++r) {
        const int srow = qt * 32 + m * 16 + lg * 4 + r;
        const int col = h * HD + nb * 16 + lr;
        AO[((size_t)b * SEQ + srow) * DEMB + col] = f2bf(o[m][nb][r] / rs[m][r]);
      }
}

// ---------------- final LN -> fp32 output -----------------------------------
__global__ void ln_out_kernel(const u16* __restrict__ src0, const float* __restrict__ bo,
                              const float* __restrict__ og, const float* __restrict__ ob,
                              float* __restrict__ out) {
  __shared__ float red[8];
  const int row = blockIdx.x;
  const u16* src = src0 + (size_t)row * DEMB;
  const int t = threadIdx.x;
  uint2 pv = *(const uint2*)(src + t * 4);
  float4 v;
  v.x = bf2f(pv.x & 0xffffu); v.y = bf2f(pv.x >> 16);
  v.z = bf2f(pv.y & 0xffffu); v.w = bf2f(pv.y >> 16);
  float4 bz = *(const float4*)(bo + t * 4);
  v.x += bz.x; v.y += bz.y; v.z += bz.z; v.w += bz.w;
  float s1 = v.x + v.y + v.z + v.w;
  float s2 = v.x * v.x + v.y * v.y + v.z * v.z + v.w * v.w;
  block_reduce2(s1, s2, red);
  const float mean = s1 * (1.f / DEMB);
  const float var = s2 * (1.f / DEMB) - mean * mean;
  const float rstd = rsqrtf(var + LN_EPS);
  float4 gg = *(const float4*)(og + t * 4);
  float4 bb = *(const float4*)(ob + t * 4);
  float4 r;
  r.x = (v.x - mean) * rstd * gg.x + bb.x;
  r.y = (v.y - mean) * rstd * gg.y + bb.y;
  r.z = (v.z - mean) * rstd * gg.z + bb.z;
  r.w = (v.w - mean) * rstd * gg.w + bb.w;
  *(float4*)(out + (size_t)row * DEMB + t * 4) = r;
}

extern "C" void kernel_launch(void* const* d_in, const int* in_sizes, int n_in,
                              void* d_out, int out_size, void* d_ws, size_t ws_size,
                              hipStream_t stream) {
  (void)in_sizes; (void)n_in; (void)out_size; (void)ws_size;
  const float* x  = (const float*)d_in[0];
  const float* Wq = (const float*)d_in[1];
  const float* bq = (const float*)d_in[2];
  const float* Wk = (const float*)d_in[3];
  const float* bk = (const float*)d_in[4];
  const float* Wv = (const float*)d_in[5];
  const float* bv = (const float*)d_in[6];
  const float* Wo = (const float*)d_in[7];
  const float* bo = (const float*)d_in[8];
  const float* qg = (const float*)d_in[9];
  const float* qb = (const float*)d_in[10];
  const float* kg = (const float*)d_in[11];
  const float* kb = (const float*)d_in[12];
  const float* vg = (const float*)d_in[13];
  const float* vb = (const float*)d_in[14];
  const float* og = (const float*)d_in[15];
  const float* ob = (const float*)d_in[16];

  // Workspace map (64 MB):
  //  [0,8)   xb (x bf16) -> Vtmp (ln_qkv V-plane) -> AO (attn out)   [serial lifetimes]
  //  [8,16)  wb  = Wq|Wk|Wv|Wo bf16
  //  [16,40) projb (QKV proj bf16) -> oprojb (out-proj bf16)
  //  [40,48) Qh   [48,56) Kh   [56,64) VT (V transposed [bh][d][s])
  char* ws = (char*)d_ws;
  u16* xb    = (u16*)(ws);
  u16* wb    = (u16*)(ws + ((size_t)8  << 20));
  u16* projb = (u16*)(ws + ((size_t)16 << 20));
  u16* Qh    = (u16*)(ws + ((size_t)40 << 20));
  u16* Kh    = (u16*)(ws + ((size_t)48 << 20));
  u16* VT    = (u16*)(ws + ((size_t)56 << 20));
  u16* Vtmp  = xb;       // alias: xb dead after QKV GEMM
  u16* AOp   = xb;       // alias: Vtmp dead after vtr
  u16* oprojb = projb;   // alias: projb dead after ln_qkv

  cvt_kernel<<<4096, 256, 0, stream>>>(x, Wq, Wk, Wv, Wo, xb, wb);

  dim3 gqkv(32, 8, 3);
  gemm_bt<<<gqkv, 256, 0, stream>>>(xb, wb, wb + (1u << 20), wb + (2u << 20),
                                    projb, MROWS, DEMB, DEMB);

  ln_qkv_kernel<<<3 * MROWS, 256, 0, stream>>>(projb, bq, bk, bv,
                                               qg, qb, kg, kb, vg, vb,
                                               Qh, Kh, Vtmp);

  vtr_kernel<<<1024, 256, 0, stream>>>(Vtmp, VT);

  attn_kernel<<<2048, 64, 0, stream>>>(Qh, Kh, VT, AOp);

  dim3 go(32, 8, 1);
  gemm_bt<<<go, 256, 0, stream>>>(AOp, wb + (3u << 20), wb + (3u << 20), wb + (3u << 20),
                                  oprojb, MROWS, DEMB, DEMB);

  ln_out_kernel<<<MROWS, 256, 0, stream>>>(oprojb, bo, og, ob, (float*)d_out);
}

// Round 7
// 252.472 us; speedup vs baseline: 1.0552x; 1.0383x over previous
//
#include <hip/hip_runtime.h>
#include <stdint.h>
#include <stddef.h>

typedef unsigned short u16;
typedef __bf16 bf16x8 __attribute__((ext_vector_type(8)));
typedef float f32x4 __attribute__((ext_vector_type(4)));
typedef u16 u16x8 __attribute__((ext_vector_type(8)));

#define SEQ    1024
#define DEMB   1024
#define MROWS  4096
#define NHEAD  16
#define HD     64
#define QSCALE 0.125f
#define LN_EPS 1e-5f

// round-to-nearest-even fp32 -> bf16 (raw bits)
static __device__ __forceinline__ u16 f2bf(float f) {
  union { float f; unsigned u; } c; c.f = f;
  unsigned r = c.u + 0x7FFFu + ((c.u >> 16) & 1u);
  return (u16)(r >> 16);
}
static __device__ __forceinline__ float bf2f(unsigned h) {
  union { unsigned u; float f; } c; c.u = h << 16; return c.f;
}

// async global->LDS, 16B per lane; LDS dest = wave-uniform base + lane*16
static __device__ __forceinline__ void gload16(const void* g, void* l) {
  __builtin_amdgcn_global_load_lds((const __attribute__((address_space(1))) void*)g,
                                   (__attribute__((address_space(3))) void*)l, 16, 0, 0);
}

// compiler-level ordering fence: forbids IR + backend motion of memory ops
static __device__ __forceinline__ void mem_fence_sched() {
  asm volatile("" ::: "memory");
  __builtin_amdgcn_sched_barrier(0);
}

// ---------------- fp32 -> bf16 convert: x (4M) + Wq/Wk/Wv/Wo (4M) -----------
__global__ void cvt_kernel(const float* __restrict__ x,
                           const float* __restrict__ wq, const float* __restrict__ wk,
                           const float* __restrict__ wv, const float* __restrict__ wo,
                           u16* __restrict__ xb, u16* __restrict__ wb) {
  size_t e = ((size_t)blockIdx.x * blockDim.x + threadIdx.x) * 8;
  const float* src; u16* dst; size_t off;
  if (e < (size_t)MROWS * DEMB) { src = x; dst = xb; off = e; }
  else {
    size_t we = e - (size_t)MROWS * DEMB;
    int plane = (int)(we >> 20);
    src = (plane == 0) ? wq : (plane == 1) ? wk : (plane == 2) ? wv : wo;
    dst = wb + ((size_t)plane << 20);
    off = we & ((1u << 20) - 1);
  }
  float4 a = *(const float4*)(src + off);
  float4 b = *(const float4*)(src + off + 4);
  u16 o[8] = { f2bf(a.x), f2bf(a.y), f2bf(a.z), f2bf(a.w),
               f2bf(b.x), f2bf(b.y), f2bf(b.z), f2bf(b.w) };
  uint4 pk;
  pk.x = (unsigned)o[0] | ((unsigned)o[1] << 16);
  pk.y = (unsigned)o[2] | ((unsigned)o[3] << 16);
  pk.z = (unsigned)o[4] | ((unsigned)o[5] << 16);
  pk.w = (unsigned)o[6] | ((unsigned)o[7] << 16);
  *(uint4*)(dst + off) = pk;
}

// ---------------- bf16 GEMM  C[m,n] = sum_k A[m,k] * W[n,k]  (bf16 out) -----
__global__ __launch_bounds__(256)
void gemm_bt(const u16* __restrict__ A, const u16* __restrict__ B0,
             const u16* __restrict__ B1, const u16* __restrict__ B2,
             u16* __restrict__ C, int M, int N, int K) {
  __shared__ u16 lA[128 * 32];
  __shared__ u16 lB[128 * 32];
  const u16* Bp = (blockIdx.z == 0) ? B0 : (blockIdx.z == 1) ? B1 : B2;
  u16* Cp = C + (size_t)blockIdx.z * ((size_t)M * N);
  const int tid = threadIdx.x;
  const int w = tid >> 6, l = tid & 63;
  const int lr = l & 15, lg = l >> 4;
  const int m0 = blockIdx.x * 128, n0 = blockIdx.y * 128;
  const int wm = (w & 1) * 64, wn = (w >> 1) * 64;
  f32x4 acc[4][4] = {};
  const int cid0 = w * 64 + l;
  const int cid1 = 256 + w * 64 + l;
  const int rowA0 = cid0 >> 2, kc0 = (cid0 & 3) * 8;
  const int rowA1 = cid1 >> 2, kc1 = (cid1 & 3) * 8;
  for (int kt = 0; kt < K; kt += 32) {
    __syncthreads();
    gload16(A  + (size_t)(m0 + rowA0) * K + kt + kc0, lA + (size_t)(w * 64) * 8);
    gload16(A  + (size_t)(m0 + rowA1) * K + kt + kc1, lA + (size_t)(256 + w * 64) * 8);
    gload16(Bp + (size_t)(n0 + rowA0) * K + kt + kc0, lB + (size_t)(w * 64) * 8);
    gload16(Bp + (size_t)(n0 + rowA1) * K + kt + kc1, lB + (size_t)(256 + w * 64) * 8);
    __syncthreads();
    bf16x8 af[4], bfg[4];
#pragma unroll
    for (int mb = 0; mb < 4; ++mb) {
      union { u16x8 u; bf16x8 v; } cv;
      cv.u = *(const u16x8*)(lA + (wm + mb * 16 + lr) * 32 + lg * 8);
      af[mb] = cv.v;
    }
#pragma unroll
    for (int nb = 0; nb < 4; ++nb) {
      union { u16x8 u; bf16x8 v; } cv;
      cv.u = *(const u16x8*)(lB + (wn + nb * 16 + lr) * 32 + lg * 8);
      bfg[nb] = cv.v;
    }
#pragma unroll
    for (int mb = 0; mb < 4; ++mb)
#pragma unroll
      for (int nb = 0; nb < 4; ++nb)
        acc[mb][nb] = __builtin_amdgcn_mfma_f32_16x16x32_bf16(af[mb], bfg[nb], acc[mb][nb], 0, 0, 0);
  }
#pragma unroll
  for (int mb = 0; mb < 4; ++mb)
#pragma unroll
    for (int nb = 0; nb < 4; ++nb)
#pragma unroll
      for (int r = 0; r < 4; ++r) {
        int row = m0 + wm + mb * 16 + lg * 4 + r;
        int col = n0 + wn + nb * 16 + lr;
        Cp[(size_t)row * N + col] = f2bf(acc[mb][nb][r]);
      }
}

// ---------------- block-wide (256t) sum + sumsq reduce ----------------------
static __device__ __forceinline__ void block_reduce2(float& s1, float& s2, float* red) {
#pragma unroll
  for (int o = 32; o > 0; o >>= 1) { s1 += __shfl_xor(s1, o); s2 += __shfl_xor(s2, o); }
  int w = threadIdx.x >> 6, l = threadIdx.x & 63;
  if (l == 0) { red[w * 2] = s1; red[w * 2 + 1] = s2; }
  __syncthreads();
  s1 = red[0] + red[2] + red[4] + red[6];
  s2 = red[1] + red[3] + red[5] + red[7];
}

// ---------------- LN over QKV proj rows -> bf16 head layout [B,H,S,64] ------
__global__ void ln_qkv_kernel(const u16* __restrict__ projb,
                              const float* __restrict__ bq, const float* __restrict__ bk,
                              const float* __restrict__ bv,
                              const float* __restrict__ qg, const float* __restrict__ qb,
                              const float* __restrict__ kg, const float* __restrict__ kb,
                              const float* __restrict__ vg, const float* __restrict__ vb,
                              u16* __restrict__ Qh, u16* __restrict__ Kh, u16* __restrict__ Vh) {
  __shared__ float red[8];
  const int row = blockIdx.x & (MROWS - 1);
  const int plane = blockIdx.x >> 12;
  const float* bias; const float* gam; const float* bet; u16* op; float scl;
  if (plane == 0)      { bias = bq; gam = qg; bet = qb; op = Qh; scl = QSCALE; }
  else if (plane == 1) { bias = bk; gam = kg; bet = kb; op = Kh; scl = 1.f; }
  else                 { bias = bv; gam = vg; bet = vb; op = Vh; scl = 1.f; }
  const u16* src = projb + ((size_t)plane * MROWS + row) * DEMB;
  const int t = threadIdx.x;
  uint2 pv = *(const uint2*)(src + t * 4);
  float4 v;
  v.x = bf2f(pv.x & 0xffffu); v.y = bf2f(pv.x >> 16);
  v.z = bf2f(pv.y & 0xffffu); v.w = bf2f(pv.y >> 16);
  float4 bz = *(const float4*)(bias + t * 4);
  v.x += bz.x; v.y += bz.y; v.z += bz.z; v.w += bz.w;
  float s1 = v.x + v.y + v.z + v.w;
  float s2 = v.x * v.x + v.y * v.y + v.z * v.z + v.w * v.w;
  block_reduce2(s1, s2, red);
  const float mean = s1 * (1.f / DEMB);
  const float var = s2 * (1.f / DEMB) - mean * mean;
  const float rstd = rsqrtf(var + LN_EPS);
  float4 gg = *(const float4*)(gam + t * 4);
  float4 bb = *(const float4*)(bet + t * 4);
  u16 o0 = f2bf(((v.x - mean) * rstd * gg.x + bb.x) * scl);
  u16 o1 = f2bf(((v.y - mean) * rstd * gg.y + bb.y) * scl);
  u16 o2 = f2bf(((v.z - mean) * rstd * gg.z + bb.z) * scl);
  u16 o3 = f2bf(((v.w - mean) * rstd * gg.w + bb.w) * scl);
  const int b = row >> 10, s = row & (SEQ - 1);
  const int h = t >> 4;
  u16* dst = op + ((size_t)(b * NHEAD + h) * SEQ + s) * HD + (t & 15) * 4;
  uint2 pk;
  pk.x = (unsigned)o0 | ((unsigned)o1 << 16);
  pk.y = (unsigned)o2 | ((unsigned)o3 << 16);
  *(uint2*)dst = pk;
}

// ---------------- V transpose: Vtmp[bh][s][d] -> VT[bh][d][s] ---------------
__global__ __launch_bounds__(256)
void vtr_kernel(const u16* __restrict__ Vtmp, u16* __restrict__ VT) {
  __shared__ u16 t[64][72];
  const int stile = blockIdx.x & 15, bh = blockIdx.x >> 4;
  const u16* src = Vtmp + ((size_t)bh * SEQ + stile * 64) * HD;
  const int tid = threadIdx.x;
  {
    const int c0 = tid * 2;
    const int r = c0 >> 3, c = c0 & 7;
    uint4 v0 = *(const uint4*)(src + (size_t)r * HD + c * 8);
    uint4 v1 = *(const uint4*)(src + (size_t)r * HD + (c + 1) * 8);
    *(uint4*)&t[r][c * 8] = v0;
    *(uint4*)&t[r][(c + 1) * 8] = v1;
  }
  __syncthreads();
  const int d = tid >> 2, sc = tid & 3;
  u16 buf[16];
#pragma unroll
  for (int j = 0; j < 16; ++j) buf[j] = t[sc * 16 + j][d];
  u16* dst = VT + ((size_t)bh * HD + d) * SEQ + stile * 64 + sc * 16;
  *(uint4*)(dst)     = *(uint4*)&buf[0];
  *(uint4*)(dst + 8) = *(uint4*)&buf[8];
}

// ---------------- attention: 128t block = 2 waves k-split over same 32 q ----
// Each wave: 32 q-rows x 512 k (8 tiles of 64). Clip-softmax is max-free so
// partial (O, rs) combine linearly via LDS at the end (1 barrier total).
// Pt access: u16 stores + u16x8 reads (type-consistent) + mem_fence_sched()
// -- round 6's NaN was TBAA-legal hoisting of the Pt read above its stores.
__global__ __launch_bounds__(128)
void attn_kernel(const u16* __restrict__ Qh, const u16* __restrict__ Kh,
                 const u16* __restrict__ VT, u16* __restrict__ AO) {
  __shared__ u16 Pt[2][32][76];      // per-wave P relayout (row stride 152B)
  __shared__ float oL[32][64];       // wave-1 partial O
  __shared__ float rsL[32];          // wave-1 partial row sums
  const int bid = blockIdx.x;
  const int wg = (bid & 7) * 256 + (bid >> 3);   // bijective: 2048 = 8*256
  const int qt = wg & 31, bh = wg >> 5;          // 8 heads per XCD chunk
  const int b = bh >> 4, h = bh & 15;
  const u16* Qp = Qh + (size_t)bh * SEQ * HD;
  const u16* Kp = Kh + (size_t)bh * SEQ * HD;
  const u16* Vp = VT + (size_t)bh * HD * SEQ;
  const int tid = threadIdx.x, w = tid >> 6, l = tid & 63;
  const int lr = l & 15, lg = l >> 4;
  bf16x8 qa[2][2];
#pragma unroll
  for (int m = 0; m < 2; ++m) {
    const u16* qr = Qp + (size_t)(qt * 32 + m * 16 + lr) * HD + lg * 8;
    union { u16x8 u; bf16x8 v; } c0, c1;
    c0.u = *(const u16x8*)qr;
    c1.u = *(const u16x8*)(qr + 32);
    qa[m][0] = c0.v; qa[m][1] = c1.v;
  }
  f32x4 o[2][4] = {};
  float rs[2][4] = {{0.f,0.f,0.f,0.f},{0.f,0.f,0.f,0.f}};
  const int kbase = w * (SEQ / 2);
  for (int t = 0; t < 8; ++t) {
    const int k0 = kbase + t * 64;
    // K fragments for this tile
    bf16x8 kf[4][2];
#pragma unroll
    for (int kb = 0; kb < 4; ++kb) {
      const u16* kr = Kp + (size_t)(k0 + kb * 16 + lr) * HD + lg * 8;
      union { u16x8 u; bf16x8 v; } c0, c1;
      c0.u = *(const u16x8*)kr;
      c1.u = *(const u16x8*)(kr + 32);
      kf[kb][0] = c0.v; kf[kb][1] = c1.v;
    }
    // QK^T + softmax numerator, one 16-q block at a time
#pragma unroll
    for (int m = 0; m < 2; ++m) {
      f32x4 sv[4];
#pragma unroll
      for (int kb = 0; kb < 4; ++kb) {
        f32x4 s0 = {};
        s0 = __builtin_amdgcn_mfma_f32_16x16x32_bf16(qa[m][0], kf[kb][0], s0, 0, 0, 0);
        s0 = __builtin_amdgcn_mfma_f32_16x16x32_bf16(qa[m][1], kf[kb][1], s0, 0, 0, 0);
        sv[kb] = s0;
      }
#pragma unroll
      for (int kb = 0; kb < 4; ++kb)
#pragma unroll
        for (int r = 0; r < 4; ++r) {
          float xx = fminf(10.f, fmaxf(-10.f, sv[kb][r]));
          float p = exp2f(xx * 1.4426950408889634f);
          rs[m][r] += p;
          Pt[w][m * 16 + lg * 4 + r][kb * 16 + lr] = f2bf(p);
        }
    }
    // order P stores before the reads below (same-wave LDS is in-order in HW;
    // this pins the compiler to program order)
    mem_fence_sched();
    // V fragments (issued before P LDS-read; latency hides under it)
    bf16x8 vf[4][2];
#pragma unroll
    for (int nb = 0; nb < 4; ++nb) {
      const u16* vr = Vp + (size_t)(nb * 16 + lr) * SEQ + k0 + lg * 8;
      union { u16x8 u; bf16x8 v; } c0, c1;
      c0.u = *(const u16x8*)vr;
      c1.u = *(const u16x8*)(vr + 32);
      vf[nb][0] = c0.v; vf[nb][1] = c1.v;
    }
    // P relayout read (intra-wave, type-consistent u16x8)
    bf16x8 pa[2][2];
#pragma unroll
    for (int m = 0; m < 2; ++m)
#pragma unroll
      for (int h2 = 0; h2 < 2; ++h2) {
        union { u16x8 u; bf16x8 v; } cv;
        cv.u = *(const u16x8*)&Pt[w][m * 16 + lr][h2 * 32 + lg * 8];
        pa[m][h2] = cv.v;
      }
    // PV
#pragma unroll
    for (int nb = 0; nb < 4; ++nb)
#pragma unroll
      for (int m = 0; m < 2; ++m) {
        o[m][nb] = __builtin_amdgcn_mfma_f32_16x16x32_bf16(pa[m][0], vf[nb][0], o[m][nb], 0, 0, 0);
        o[m][nb] = __builtin_amdgcn_mfma_f32_16x16x32_bf16(pa[m][1], vf[nb][1], o[m][nb], 0, 0, 0);
      }
    // keep next iteration's P stores below this iteration's P reads
    mem_fence_sched();
  }
  // complete row sums across the 16 lanes sharing lg (lr bits 0..3 = col id)
#pragma unroll
  for (int m = 0; m < 2; ++m)
#pragma unroll
    for (int r = 0; r < 4; ++r) {
      float vsum = rs[m][r];
      vsum += __shfl_xor(vsum, 1);
      vsum += __shfl_xor(vsum, 2);
      vsum += __shfl_xor(vsum, 4);
      vsum += __shfl_xor(vsum, 8);
      rs[m][r] = vsum;
    }
  // combine the two k-half partials
  if (w == 1) {
#pragma unroll
    for (int m = 0; m < 2; ++m)
#pragma unroll
      for (int nb = 0; nb < 4; ++nb)
#pragma unroll
        for (int r = 0; r < 4; ++r)
          oL[m * 16 + lg * 4 + r][nb * 16 + lr] = o[m][nb][r];
    if (lr == 0) {
#pragma unroll
      for (int m = 0; m < 2; ++m)
#pragma unroll
        for (int r = 0; r < 4; ++r)
          rsL[m * 16 + lg * 4 + r] = rs[m][r];
    }
  }
  __syncthreads();
  if (w == 0) {
#pragma unroll
    for (int m = 0; m < 2; ++m)
#pragma unroll
      for (int r = 0; r < 4; ++r) {
        const int row = m * 16 + lg * 4 + r;
        const float inv = 1.f / (rs[m][r] + rsL[row]);
        const int srow = qt * 32 + row;
#pragma unroll
        for (int nb = 0; nb < 4; ++nb) {
          float tot = (o[m][nb][r] + oL[row][nb * 16 + lr]) * inv;
          AO[((size_t)b * SEQ + srow) * DEMB + h * HD + nb * 16 + lr] = f2bf(tot);
        }
      }
  }
}

// ---------------- final LN -> fp32 output -----------------------------------
__global__ void ln_out_kernel(const u16* __restrict__ src0, const float* __restrict__ bo,
                              const float* __restrict__ og, const float* __restrict__ ob,
                              float* __restrict__ out) {
  __shared__ float red[8];
  const int row = blockIdx.x;
  const u16* src = src0 + (size_t)row * DEMB;
  const int t = threadIdx.x;
  uint2 pv = *(const uint2*)(src + t * 4);
  float4 v;
  v.x = bf2f(pv.x & 0xffffu); v.y = bf2f(pv.x >> 16);
  v.z = bf2f(pv.y & 0xffffu); v.w = bf2f(pv.y >> 16);
  float4 bz = *(const float4*)(bo + t * 4);
  v.x += bz.x; v.y += bz.y; v.z += bz.z; v.w += bz.w;
  float s1 = v.x + v.y + v.z + v.w;
  float s2 = v.x * v.x + v.y * v.y + v.z * v.z + v.w * v.w;
  block_reduce2(s1, s2, red);
  const float mean = s1 * (1.f / DEMB);
  const float var = s2 * (1.f / DEMB) - mean * mean;
  const float rstd = rsqrtf(var + LN_EPS);
  float4 gg = *(const float4*)(og + t * 4);
  float4 bb = *(const float4*)(ob + t * 4);
  float4 r;
  r.x = (v.x - mean) * rstd * gg.x + bb.x;
  r.y = (v.y - mean) * rstd * gg.y + bb.y;
  r.z = (v.z - mean) * rstd * gg.z + bb.z;
  r.w = (v.w - mean) * rstd * gg.w + bb.w;
  *(float4*)(out + (size_t)row * DEMB + t * 4) = r;
}

extern "C" void kernel_launch(void* const* d_in, const int* in_sizes, int n_in,
                              void* d_out, int out_size, void* d_ws, size_t ws_size,
                              hipStream_t stream) {
  (void)in_sizes; (void)n_in; (void)out_size; (void)ws_size;
  const float* x  = (const float*)d_in[0];
  const float* Wq = (const float*)d_in[1];
  const float* bq = (const float*)d_in[2];
  const float* Wk = (const float*)d_in[3];
  const float* bk = (const float*)d_in[4];
  const float* Wv = (const float*)d_in[5];
  const float* bv = (const float*)d_in[6];
  const float* Wo = (const float*)d_in[7];
  const float* bo = (const float*)d_in[8];
  const float* qg = (const float*)d_in[9];
  const float* qb = (const float*)d_in[10];
  const float* kg = (const float*)d_in[11];
  const float* kb = (const float*)d_in[12];
  const float* vg = (const float*)d_in[13];
  const float* vb = (const float*)d_in[14];
  const float* og = (const float*)d_in[15];
  const float* ob = (const float*)d_in[16];

  // Workspace map (64 MB):
  //  [0,8)   xb (x bf16) -> Vtmp (ln_qkv V-plane) -> AO (attn out)
  //  [8,16)  wb  = Wq|Wk|Wv|Wo bf16
  //  [16,40) projb (QKV proj bf16) -> oprojb (out-proj bf16)
  //  [40,48) Qh   [48,56) Kh   [56,64) VT (V transposed [bh][d][s])
  char* ws = (char*)d_ws;
  u16* xb    = (u16*)(ws);
  u16* wb    = (u16*)(ws + ((size_t)8  << 20));
  u16* projb = (u16*)(ws + ((size_t)16 << 20));
  u16* Qh    = (u16*)(ws + ((size_t)40 << 20));
  u16* Kh    = (u16*)(ws + ((size_t)48 << 20));
  u16* VT    = (u16*)(ws + ((size_t)56 << 20));
  u16* Vtmp  = xb;
  u16* AOp   = xb;
  u16* oprojb = projb;

  cvt_kernel<<<4096, 256, 0, stream>>>(x, Wq, Wk, Wv, Wo, xb, wb);

  dim3 gqkv(32, 8, 3);
  gemm_bt<<<gqkv, 256, 0, stream>>>(xb, wb, wb + (1u << 20), wb + (2u << 20),
                                    projb, MROWS, DEMB, DEMB);

  ln_qkv_kernel<<<3 * MROWS, 256, 0, stream>>>(projb, bq, bk, bv,
                                               qg, qb, kg, kb, vg, vb,
                                               Qh, Kh, Vtmp);

  vtr_kernel<<<1024, 256, 0, stream>>>(Vtmp, VT);

  attn_kernel<<<2048, 128, 0, stream>>>(Qh, Kh, VT, AOp);

  dim3 go(32, 8, 1);
  gemm_bt<<<go, 256, 0, stream>>>(AOp, wb + (3u << 20), wb + (3u << 20), wb + (3u << 20),
                                  oprojb, MROWS, DEMB, DEMB);

  ln_out_kernel<<<MROWS, 256, 0, stream>>>(oprojb, bo, og, ob, (float*)d_out);
}